// Round 2
// baseline (5573.754 us; speedup 1.0000x reference)
//
#include <hip/hip_runtime.h>
#include <hip/hip_bf16.h>

// Bidirectional ConvLSTM, B=8 T=16 C=3 H=W=32 hid=64 K=7 ('SAME').
// Dtype-adaptive: a probe kernel detects whether d_in is fp32 or bf16 at
// runtime (device-side flag; all branching on-device, graph-capture safe).
// Compute is fp32 VALU; weights/h-state stored as repacked bf16 in ws.
//
// Workspace layout (BYTE offsets), total 14,264,324 B:
//   hp0 : padded h ping,  bf16 [dir][b][ch64][38][40]  @ 0        (3,112,960 B)
//   hp1 : padded h pong,  bf16                          @ 3112960  (3,112,960 B)
//   c   : cell state,     fp32 [dir][b][ch64][32][32]   @ 6225920  (4,194,304 B)
//   w_r : hh weights,     bf16 [dir][ic64][ky7][g4][hid64][kx8] @ 10420224 (3,670,016 B)
//   wi_r: ih weights,     bf16 [dir][ic3][ky7][g4][hid64][kx8]  @ 14090240 (172,032 B)
//   bias: fp32 [dir][256]                               @ 14262272 (2,048 B)
//   flag: int (1 = inputs are fp32, 0 = bf16)           @ 14264320 (4 B)

#define WPAD 40
#define HPAD 38
#define PLANE (HPAD * WPAD) // 1520

#define HP0_B  0
#define HP1_B  3112960
#define C_B    6225920
#define WR_B   10420224
#define WIR_B  14090240
#define BIAS_B 14262272
#define FLAG_B 14264320

__device__ __forceinline__ float sigm(float x) { return 1.0f / (1.0f + __expf(-x)); }
__device__ __forceinline__ float tanh_f(float x) {
    x = fminf(fmaxf(x, -30.0f), 30.0f);
    float e = __expf(2.0f * x);
    return (e - 1.0f) / (e + 1.0f);
}

// ---- dtype probe: low 16 bits of fp32 mantissas have uniform "exponent"
// bits when read as bf16 (~25% >= 0xC0); genuine bf16 N(0,1) data never does.
__global__ void detect_dtype(const unsigned int* __restrict__ xw, int* __restrict__ flag) {
    int lane = threadIdx.x; // 64 lanes
    int cnt = 0;
    for (int i = 0; i < 4; ++i) {
        unsigned int w = xw[lane * 4 + i];
        unsigned int e = (w >> 7) & 0xFFu; // exponent of LOW half as bf16
        cnt += (e >= 0xC0u) ? 1 : 0;
    }
#pragma unroll
    for (int off = 32; off > 0; off >>= 1) cnt += __shfl_down(cnt, off, 64);
    if (lane == 0) *flag = (cnt > 16) ? 1 : 0;
}

// ---- weights -> canonical bf16 repack -----------------------------------
__global__ void prep_weights(const void* __restrict__ whhf, const void* __restrict__ whhb,
                             const void* __restrict__ wihf, const void* __restrict__ wihb,
                             const void* __restrict__ bf, const void* __restrict__ bb,
                             __hip_bfloat16* __restrict__ w_r, __hip_bfloat16* __restrict__ wi_r,
                             float* __restrict__ bias_r, const int* __restrict__ flag) {
    int n = blockIdx.x * blockDim.x + threadIdx.x;
    const int fp32 = *flag;
    const int TOT_HH = 2 * 917504;
    const int TOT_IH = 2 * 43008;
    if (n < TOT_HH) {
        int d = n / 917504, m = n % 917504;
        int kx = m % 8, hid = (m / 8) % 64, g = (m / 512) % 4, ky = (m / 2048) % 7, ic = m / 14336;
        const void* src = d ? whhb : whhf;
        __hip_bfloat16 v = __float2bfloat16(0.0f);
        if (kx < 7) {
            int si = (((g * 64 + hid) * 64 + ic) * 7 + ky) * 7 + kx;
            v = fp32 ? __float2bfloat16(((const float*)src)[si])
                     : ((const __hip_bfloat16*)src)[si];
        }
        w_r[n] = v;
        return;
    }
    n -= TOT_HH;
    if (n < TOT_IH) {
        int d = n / 43008, m = n % 43008;
        int kx = m % 8, hid = (m / 8) % 64, g = (m / 512) % 4, ky = (m / 2048) % 7, ic = m / 14336;
        const void* src = d ? wihb : wihf;
        __hip_bfloat16 v = __float2bfloat16(0.0f);
        if (kx < 7) {
            int si = (((g * 64 + hid) * 3 + ic) * 7 + ky) * 7 + kx;
            v = fp32 ? __float2bfloat16(((const float*)src)[si])
                     : ((const __hip_bfloat16*)src)[si];
        }
        wi_r[n] = v;
        return;
    }
    n -= TOT_IH;
    if (n < 512) {
        int d = n / 256, j = n % 256;
        const void* src = d ? bb : bf;
        bias_r[n] = fp32 ? ((const float*)src)[j]
                         : __bfloat162float(((const __hip_bfloat16*)src)[j]);
    }
}

// ---- zero hp0+hp1+c (contiguous 2,605,056 dwords at ws start) -----------
__global__ void zero_state(float* __restrict__ ws_f) {
    int n = blockIdx.x * blockDim.x + threadIdx.x;
    if (n < 2605056) ws_f[n] = 0.0f;
}

// ---- one recurrence step, both dirs; ping-pong h ------------------------
// grid (32 y, 8 b, 2 dir), 256 thr: hid = tid>>2, x-octet = tid&3.
__global__ __launch_bounds__(256, 2)
void lstm_step(const void* __restrict__ xin,
               const __hip_bfloat16* __restrict__ w_r,
               const __hip_bfloat16* __restrict__ wi_r,
               const float* __restrict__ bias_r,
               const __hip_bfloat16* __restrict__ hp_r,
               __hip_bfloat16* __restrict__ hp_w,
               float* __restrict__ c,
               void* __restrict__ out,
               const int* __restrict__ flag, int s) {
    const int y0 = blockIdx.x;
    const int b = blockIdx.y;
    const int dir = blockIdx.z;
    const int t = dir ? (15 - s) : s;
    const int tid = threadIdx.x;
    const int hid = tid >> 2;
    const int x0 = (tid & 3) * 8;
    const int fp32 = *flag;

    __shared__ float lds[32 * 7 * WPAD]; // 35,840 B

    float acc[4][8];
#pragma unroll
    for (int g = 0; g < 4; ++g) {
        float bv = bias_r[dir * 256 + g * 64 + hid];
#pragma unroll
        for (int xx = 0; xx < 8; ++xx) acc[g][xx] = bv;
    }

    const __hip_bfloat16* hp_b = hp_r + (size_t)(dir * 8 + b) * 64 * PLANE;

    for (int chunk = 0; chunk < 3; ++chunk) {
        __syncthreads();
        if (chunk < 2) {
            const __hip_bfloat16* src = hp_b + chunk * 32 * PLANE;
            for (int i = tid; i < 32 * 7 * WPAD; i += 256) {
                int ic = i / (7 * WPAD), rem = i % (7 * WPAD);
                int r = rem / WPAD, px = rem % WPAD;
                lds[i] = __bfloat162float(src[ic * PLANE + (y0 + r) * WPAD + px]);
            }
        } else {
            for (int i = tid; i < 3 * 7 * WPAD; i += 256) {
                int ic = i / (7 * WPAD), rem = i % (7 * WPAD);
                int r = rem / WPAD, px = rem % WPAD;
                int yy = y0 + r - 3, xx2 = px - 3;
                float v = 0.0f;
                if (yy >= 0 && yy < 32 && xx2 >= 0 && xx2 < 32) {
                    int gi = ((b * 16 + t) * 3 + ic) * 1024 + yy * 32 + xx2;
                    v = fp32 ? ((const float*)xin)[gi]
                             : __bfloat162float(((const __hip_bfloat16*)xin)[gi]);
                }
                lds[i] = v;
            }
        }
        __syncthreads();
        const int nch = (chunk < 2) ? 32 : 3;
        const __hip_bfloat16* wbase = (chunk < 2)
            ? (w_r + (size_t)(dir * 64 + chunk * 32) * 14336)
            : (wi_r + (size_t)dir * 43008);
        for (int ic = 0; ic < nch; ++ic) {
            for (int ky = 0; ky < 7; ++ky) {
                float inv[14];
#pragma unroll
                for (int j = 0; j < 14; ++j)
                    inv[j] = lds[ic * (7 * WPAD) + ky * WPAD + x0 + j];
                const uint4* wp = reinterpret_cast<const uint4*>(wbase + (size_t)(ic * 7 + ky) * 2048);
#pragma unroll
                for (int g = 0; g < 4; ++g) {
                    uint4 W = wp[g * 64 + hid];
                    float wv[7];
                    wv[0] = __uint_as_float(W.x << 16);
                    wv[1] = __uint_as_float(W.x & 0xFFFF0000u);
                    wv[2] = __uint_as_float(W.y << 16);
                    wv[3] = __uint_as_float(W.y & 0xFFFF0000u);
                    wv[4] = __uint_as_float(W.z << 16);
                    wv[5] = __uint_as_float(W.z & 0xFFFF0000u);
                    wv[6] = __uint_as_float(W.w << 16);
#pragma unroll
                    for (int kx = 0; kx < 7; ++kx)
#pragma unroll
                        for (int xx = 0; xx < 8; ++xx)
                            acc[g][xx] = fmaf(wv[kx], inv[xx + kx], acc[g][xx]);
                }
            }
        }
    }

    // epilogue
    __hip_bfloat16* hw = hp_w + ((size_t)(dir * 8 + b) * 64 + hid) * PLANE;
    float* cp = c + ((size_t)(dir * 8 + b) * 64 + hid) * 1024;
    size_t obase = ((size_t)((b * 16 + t) * 128 + dir * 64 + hid)) * 1024 + (size_t)y0 * 32;
#pragma unroll
    for (int xx = 0; xx < 8; ++xx) {
        int x = x0 + xx;
        float iv = sigm(acc[0][xx]);
        float fv = sigm(acc[1][xx]);
        float gv = tanh_f(acc[2][xx]);
        float ov = sigm(acc[3][xx]);
        float cn = fv * cp[y0 * 32 + x] + iv * gv;
        cp[y0 * 32 + x] = cn;
        float h = ov * tanh_f(cn);
        __hip_bfloat16 hb = __float2bfloat16(h);
        hw[(y0 + 3) * WPAD + (x + 3)] = hb;
        if (fp32) ((float*)out)[obase + x] = h;
        else      ((__hip_bfloat16*)out)[obase + x] = hb;
    }
}

extern "C" void kernel_launch(void* const* d_in, const int* in_sizes, int n_in,
                              void* d_out, int out_size, void* d_ws, size_t ws_size,
                              hipStream_t stream) {
    char* wsb = (char*)d_ws;
    __hip_bfloat16* hp0 = (__hip_bfloat16*)(wsb + HP0_B);
    __hip_bfloat16* hp1 = (__hip_bfloat16*)(wsb + HP1_B);
    float* c = (float*)(wsb + C_B);
    __hip_bfloat16* w_r = (__hip_bfloat16*)(wsb + WR_B);
    __hip_bfloat16* wi_r = (__hip_bfloat16*)(wsb + WIR_B);
    float* bias_r = (float*)(wsb + BIAS_B);
    int* flag = (int*)(wsb + FLAG_B);

    // inputs: 0=x 1=w_ih_f 2=w_hh_f 3=b_f 4=w_ih_b 5=w_hh_b 6=b_b
    detect_dtype<<<1, 64, 0, stream>>>((const unsigned int*)d_in[0], flag);
    prep_weights<<<7506, 256, 0, stream>>>(d_in[2], d_in[5], d_in[1], d_in[4],
                                           d_in[3], d_in[6], w_r, wi_r, bias_r, flag);
    zero_state<<<10176, 256, 0, stream>>>((float*)d_ws);

    for (int s = 0; s < 16; ++s) {
        __hip_bfloat16* hr = (s & 1) ? hp1 : hp0;
        __hip_bfloat16* hw = (s & 1) ? hp0 : hp1;
        lstm_step<<<dim3(32, 8, 2), 256, 0, stream>>>(d_in[0], w_r, wi_r, bias_r,
                                                      hr, hw, c, d_out, flag, s);
    }
}

// Round 3
// 663.584 us; speedup vs baseline: 8.3995x; 8.3995x over previous
//
#include <hip/hip_runtime.h>
#include <hip/hip_bf16.h>

// Bidirectional ConvLSTM, B=8 T=16 C=3 H=W=32 hid=64 K=7 ('SAME').
// Round 3: MFMA implicit-GEMM step kernel (16x16x32 bf16).
//   M=256 oc (4 gates x 64 hid), N=64 px (2 rows), K=105 steps of 32:
//     ks 0..97  : h-conv, k=ic chunk (kc*32+..), (ky,kx) via LDS addr shift
//     ks 98..104: x-conv, k=(ky*4+ic) packed XB tile, kx via addr shift
//   4 waves M-split: wave w owns hid[16w,16w+16) for all 4 gates -> in-wave epilogue.
// Dtype-adaptive (fp32 or bf16 inputs) via device-side flag, as round 2.
//
// Workspace (BYTE offsets), total 13,862,916 B:
//   hp0 : padded h ping, bf16 [dir][b][row38][col40][ic64] @ 0        (3,112,960)
//   hp1 : padded h pong                                    @ 3112960  (3,112,960)
//   c   : cell,  fp32 [dir][b][y32][x32][hid64]            @ 6225920  (4,194,304)
//   wall: bf16 [dir][ks105][oc256][k32]                    @ 10420224 (3,440,640)
//   bias: fp32 [dir][256]                                  @ 13860864 (2,048)
//   flag: int (1 = fp32 inputs)                            @ 13862912 (4)

#define HP0_B  0
#define HP1_B  3112960
#define C_B    6225920
#define WALL_B 10420224
#define BIAS_B 13860864
#define FLAG_B 13862912

using short8 = __attribute__((ext_vector_type(8))) short;
using f32x4  = __attribute__((ext_vector_type(4))) float;

__device__ __forceinline__ float sigm(float x) { return 1.0f / (1.0f + __expf(-x)); }
__device__ __forceinline__ float tanh_f(float x) {
    x = fminf(fmaxf(x, -30.0f), 30.0f);
    float e = __expf(2.0f * x);
    return (e - 1.0f) / (e + 1.0f);
}

// ---- dtype probe (round-2, verified) ------------------------------------
__global__ void detect_dtype(const unsigned int* __restrict__ xw, int* __restrict__ flag) {
    int lane = threadIdx.x;
    int cnt = 0;
    for (int i = 0; i < 4; ++i) {
        unsigned int w = xw[lane * 4 + i];
        unsigned int e = (w >> 7) & 0xFFu;
        cnt += (e >= 0xC0u) ? 1 : 0;
    }
#pragma unroll
    for (int off = 32; off > 0; off >>= 1) cnt += __shfl_down(cnt, off, 64);
    if (lane == 0) *flag = (cnt > 16) ? 1 : 0;
}

// ---- weights -> wall[d][ks][oc][k32] bf16 + bias ------------------------
__global__ void prep_weights(const void* __restrict__ whhf, const void* __restrict__ whhb,
                             const void* __restrict__ wihf, const void* __restrict__ wihb,
                             const void* __restrict__ bf, const void* __restrict__ bb,
                             short* __restrict__ wall, float* __restrict__ bias_r,
                             const int* __restrict__ flag) {
    int n = blockIdx.x * blockDim.x + threadIdx.x;
    const int fp32 = *flag;
    if (n < 1720320) {
        int icl = n & 31;
        int oc = (n >> 5) & 255;
        int ks = (n >> 13) % 105;
        int d = n / 860160;
        const void* hh = d ? whhb : whhf;
        const void* ih = d ? wihb : wihf;
        float v = 0.0f;
        if (ks < 98) {
            int ky = ks / 14, rr = ks % 14, kc = rr / 7, kx = rr % 7;
            int si = ((oc * 64 + kc * 32 + icl) * 7 + ky) * 7 + kx;
            v = fp32 ? ((const float*)hh)[si] : __bfloat162float(((const __hip_bfloat16*)hh)[si]);
        } else {
            int kx = ks - 98, ky = icl >> 2, ic = icl & 3;
            if (ic < 3 && ky < 7) {
                int si = ((oc * 3 + ic) * 7 + ky) * 7 + kx;
                v = fp32 ? ((const float*)ih)[si] : __bfloat162float(((const __hip_bfloat16*)ih)[si]);
            }
        }
        __hip_bfloat16 hv = __float2bfloat16(v);
        wall[n] = *(short*)&hv;
        return;
    }
    n -= 1720320;
    if (n < 512) {
        const void* src = (n >= 256) ? bb : bf;
        int j = n & 255;
        bias_r[n] = fp32 ? ((const float*)src)[j] : __bfloat162float(((const __hip_bfloat16*)src)[j]);
    }
}

// ---- zero hp0+hp1+c (contiguous 2,605,056 dwords at ws start) -----------
__global__ void zero_state(float* __restrict__ ws_f) {
    int n = blockIdx.x * blockDim.x + threadIdx.x;
    if (n < 2605056) ws_f[n] = 0.0f;
}

// ---- MFMA step kernel ----------------------------------------------------
// grid (16 ygrp, 8 b, 2 dir), 256 thr = 4 waves.
// LDS: h tile [8 rows][40 cols][72 icpad] = 23040 shorts (46,080 B)
//      XB     [2 rows][40 cols][40 kpad]  =  3200 shorts ( 6,400 B)
__global__ __launch_bounds__(256, 1)
void lstm_step(const void* __restrict__ xin,
               const short* __restrict__ wall,
               const float* __restrict__ bias_r,
               const unsigned short* __restrict__ hp_r,
               unsigned short* __restrict__ hp_w,
               float* __restrict__ c,
               void* __restrict__ out,
               const int* __restrict__ flag, int s) {
    const int ygrp = blockIdx.x;
    const int b = blockIdx.y;
    const int dir = blockIdx.z;
    const int t = dir ? (15 - s) : s;
    const int y0 = ygrp * 2;
    const int tid = threadIdx.x;
    const int w = tid >> 6;
    const int l = tid & 63;
    const int q = l >> 4;
    const int li = l & 15;
    const int fp32 = *flag;
    const int db = dir * 8 + b;

    __shared__ short lds[23040 + 3200];

    // stage h rows y0..y0+7 (contiguous in global) into padded LDS
    {
        const uint4* src = (const uint4*)(hp_r + (size_t)(db * 38 + y0) * 40 * 64);
        for (int i = tid; i < 2560; i += 256) {
            int ic8 = i & 7, col = (i >> 3) % 40, row = i / 320;
            uint4 v = src[i];
            *(uint4*)&lds[(row * 40 + col) * 72 + ic8 * 8] = v;
        }
    }
    // build XB[r][c][k=ky*4+ic]
    for (int i = tid; i < 3200; i += 256) {
        int k = i % 40, cc = (i / 40) % 40, r = i / 1600;
        float v = 0.0f;
        if (k < 28) {
            int ky = k >> 2, ic = k & 3;
            int yin = y0 + r + ky - 3, cin = cc - 3;
            if (ic < 3 && yin >= 0 && yin < 32 && cin >= 0 && cin < 32) {
                size_t gi = (size_t)((b * 16 + t) * 3 + ic) * 1024 + yin * 32 + cin;
                v = fp32 ? ((const float*)xin)[gi]
                         : __bfloat162float(((const __hip_bfloat16*)xin)[gi]);
            }
        }
        __hip_bfloat16 hb = __float2bfloat16(v);
        lds[23040 + i] = *(short*)&hb;
    }
    __syncthreads();

    // acc init from bias: C/D row = q*4+r -> hid0 = w*16 + q*4
    f32x4 acc[4][4];
    {
        const float* bp = bias_r + dir * 256 + w * 16 + q * 4;
#pragma unroll
        for (int g = 0; g < 4; ++g) {
            f32x4 bv = *(const f32x4*)(bp + g * 64);
#pragma unroll
            for (int nt = 0; nt < 4; ++nt) acc[g][nt] = bv;
        }
    }

    // lane bases
    const short* wbase = wall + (size_t)dir * 860160 + ((w * 16 + li) * 32 + q * 8);
    int bh[4], bx[4];
#pragma unroll
    for (int nt = 0; nt < 4; ++nt) {
        int rt = nt >> 1, ct = nt & 1;
        bh[nt] = (rt * 40 + ct * 16 + li) * 72 + q * 8;
        bx[nt] = 23040 + (rt * 40 + ct * 16 + li) * 40 + q * 8;
    }

    auto loadA = [&](short8* A, int ks) {
        const short* p = wbase + (size_t)ks * 8192;
#pragma unroll
        for (int g = 0; g < 4; ++g) A[g] = *(const short8*)(p + g * 2048);
    };
    auto loadB = [&](short8* B, int ks) {
        if (ks < 98) {
            int ky = ks / 14, rr = ks % 14;
            int uoff = ky * 2880 + (rr % 7) * 72 + (rr / 7) * 32;
#pragma unroll
            for (int nt = 0; nt < 4; ++nt) B[nt] = *(const short8*)&lds[bh[nt] + uoff];
        } else {
            int uoff = (ks - 98) * 40;
#pragma unroll
            for (int nt = 0; nt < 4; ++nt) B[nt] = *(const short8*)&lds[bx[nt] + uoff];
        }
    };
    auto mfma16 = [&](short8* A, short8* B) {
#pragma unroll
        for (int g = 0; g < 4; ++g)
#pragma unroll
            for (int nt = 0; nt < 4; ++nt)
                acc[g][nt] = __builtin_amdgcn_mfma_f32_16x16x32_bf16(A[g], B[nt], acc[g][nt], 0, 0, 0);
    };

    short8 A0[4], A1[4], B0[4], B1[4];
    loadA(A0, 0); loadB(B0, 0);
#pragma unroll 1
    for (int ks = 0; ks < 104; ks += 2) {
        loadA(A1, ks + 1); loadB(B1, ks + 1);
        mfma16(A0, B0);
        loadA(A0, ks + 2); loadB(B0, ks + 2);
        mfma16(A1, B1);
    }
    mfma16(A0, B0); // ks = 104

    // epilogue (in-wave: all 4 gates present)
    const int hid0 = w * 16 + q * 4;
#pragma unroll
    for (int nt = 0; nt < 4; ++nt) {
        int y = y0 + (nt >> 1);
        int px = (nt & 1) * 16 + li;
        float* cp = c + (size_t)(db * 1024 + y * 32 + px) * 64 + hid0;
        f32x4 cold = *(const f32x4*)cp;
        f32x4 hv;
#pragma unroll
        for (int r = 0; r < 4; ++r) {
            float iv = sigm(acc[0][nt][r]);
            float fv = sigm(acc[1][nt][r]);
            float gv = tanh_f(acc[2][nt][r]);
            float ov = sigm(acc[3][nt][r]);
            float cn = fv * cold[r] + iv * gv;
            cold[r] = cn;
            hv[r] = ov * tanh_f(cn);
        }
        *(f32x4*)cp = cold;

        ushort4 hu;
        {
            __hip_bfloat16 t0 = __float2bfloat16(hv[0]); hu.x = *(unsigned short*)&t0;
            __hip_bfloat16 t1 = __float2bfloat16(hv[1]); hu.y = *(unsigned short*)&t1;
            __hip_bfloat16 t2 = __float2bfloat16(hv[2]); hu.z = *(unsigned short*)&t2;
            __hip_bfloat16 t3 = __float2bfloat16(hv[3]); hu.w = *(unsigned short*)&t3;
        }
        *(ushort4*)(hp_w + (size_t)((db * 38 + y + 3) * 40 + px + 3) * 64 + hid0) = hu;

        size_t ob = (size_t)((b * 16 + t) * 128 + dir * 64 + hid0) * 1024 + y * 32 + px;
        if (fp32) {
            float* op = (float*)out;
#pragma unroll
            for (int r = 0; r < 4; ++r) op[ob + (size_t)r * 1024] = hv[r];
        } else {
            __hip_bfloat16* op = (__hip_bfloat16*)out;
#pragma unroll
            for (int r = 0; r < 4; ++r) op[ob + (size_t)r * 1024] = __float2bfloat16(hv[r]);
        }
    }
}

extern "C" void kernel_launch(void* const* d_in, const int* in_sizes, int n_in,
                              void* d_out, int out_size, void* d_ws, size_t ws_size,
                              hipStream_t stream) {
    char* wsb = (char*)d_ws;
    unsigned short* hp0 = (unsigned short*)(wsb + HP0_B);
    unsigned short* hp1 = (unsigned short*)(wsb + HP1_B);
    float* c = (float*)(wsb + C_B);
    short* wall = (short*)(wsb + WALL_B);
    float* bias_r = (float*)(wsb + BIAS_B);
    int* flag = (int*)(wsb + FLAG_B);

    // inputs: 0=x 1=w_ih_f 2=w_hh_f 3=b_f 4=w_ih_b 5=w_hh_b 6=b_b
    detect_dtype<<<1, 64, 0, stream>>>((const unsigned int*)d_in[0], flag);
    prep_weights<<<6722, 256, 0, stream>>>(d_in[2], d_in[5], d_in[1], d_in[4],
                                           d_in[3], d_in[6], wall, bias_r, flag);
    zero_state<<<10176, 256, 0, stream>>>((float*)d_ws);

    for (int s = 0; s < 16; ++s) {
        unsigned short* hr = (s & 1) ? hp1 : hp0;
        unsigned short* hw = (s & 1) ? hp0 : hp1;
        lstm_step<<<dim3(16, 8, 2), 256, 0, stream>>>(d_in[0], wall, bias_r,
                                                      hr, hw, c, d_out, flag, s);
    }
}